// Round 15
// baseline (336.350 us; speedup 1.0000x reference)
//
#include <hip/hip_runtime.h>
#include <math.h>

#define BATCH 8
#define SEQ   2048
#define DM    256
#define DQK   128
#define NHEADS 8
#define NK    16
#define DFF   1024

typedef __attribute__((ext_vector_type(8))) short short8;
typedef __attribute__((ext_vector_type(8))) _Float16 half8;
typedef __attribute__((ext_vector_type(4))) float floatx4;
typedef unsigned long long ull;

__device__ __forceinline__ unsigned short f2bf(float f) {
    unsigned int u = __float_as_uint(f);
    u += 0x7fffu + ((u >> 16) & 1u);          // round-to-nearest-even
    return (unsigned short)(u >> 16);
}

__device__ __forceinline__ float gelu_fast(float h) {
    float y = 0.7978845608028654f * (h + 0.044715f * h * h * h);
    float e = __expf(2.f * y);
    float t = 1.f - 2.f / (e + 1.f);
    return 0.5f * h * (1.f + t);
}

// composite sort key: primary score desc, secondary idx asc. Unique per idx.
__device__ __forceinline__ ull mkkey(float f, int gidx) {
    unsigned int u = __float_as_uint(f);
    u ^= (unsigned int)((int)u >> 31) | 0x80000000u;   // sortable float
    return ((ull)u << 32) | (unsigned int)(2047 - gidx);
}

__device__ __forceinline__ ull shfl_xor_u64(ull v, int m) {
    unsigned int lo = (unsigned int)v, hi = (unsigned int)(v >> 32);
    lo = __shfl_xor(lo, m);
    hi = __shfl_xor(hi, m);
    return ((ull)hi << 32) | lo;
}

// ---------------------------------------------------------------------------
// Kernel W: repack W1/W2/Wv/Wo fp32 -> bf16 MFMA B-fragment order (verbatim).
// ---------------------------------------------------------------------------
__global__ __launch_bounds__(256) void conv_kernel(
    const float* __restrict__ W1, const float* __restrict__ W2,
    const float* __restrict__ Wv, const float* __restrict__ Wo,
    unsigned short* __restrict__ W1f, unsigned short* __restrict__ W2f,
    unsigned short* __restrict__ Wvf, unsigned short* __restrict__ Wof)
{
    int g = blockIdx.x * 256 + threadIdx.x;
    const float* W; unsigned short* O; int e, stride;
    if (g < 32768)      { W = W1; O = W1f; e = g;         stride = DFF; }
    else if (g < 65536) { W = W2; O = W2f; e = g - 32768; stride = DM;  }
    else if (g < 73728) { W = Wv; O = Wvf; e = g - 65536; stride = DM;  }
    else                { W = Wo; O = Wof; e = g - 73728; stride = DM;  }
    int lane = e & 63;
    int kk, nt;
    if (g < 32768)      { kk = (e >> 6) & 7;  nt = e >> 9;  }
    else if (g < 65536) { kk = (e >> 6) & 31; nt = e >> 11; }
    else                { kk = (e >> 6) & 7;  nt = e >> 9;  }
    int n = nt * 16 + (lane & 15);
    int k0 = kk * 32 + (lane >> 4) * 8;
    unsigned int pk[4];
    #pragma unroll
    for (int jj = 0; jj < 4; ++jj) {
        unsigned short lo = f2bf(W[(size_t)(k0 + 2 * jj) * stride + n]);
        unsigned short hi = f2bf(W[(size_t)(k0 + 2 * jj + 1) * stride + n]);
        pk[jj] = (unsigned int)lo | ((unsigned int)hi << 16);
    }
    *(uint4*)(O + (size_t)e * 8) = make_uint4(pk[0], pk[1], pk[2], pk[3]);
}

// ---------------------------------------------------------------------------
// Kernel P: MERGED projections, INTERLEAVED dispatch: bid%3==2 -> proj_v
// (vidx=bid/3, 1024 blocks), else -> proj_qk (qkidx=(bid/3)*2+bid%3, 2048
// blocks, bijective). Consecutive blocks round-robin across CUs, so every
// CU holds a mix of VALU-bound qk and MFMA-bound v blocks from the start
// (m114: separate pipes co-schedule, time ~ max not sum). Both paths'
// math verbatim -> bit-identical outputs.
// ---------------------------------------------------------------------------
__global__ __launch_bounds__(256) void proj_merged_kernel(
    const float* __restrict__ x,
    const float* __restrict__ Wq, const float* __restrict__ bq,
    const float* __restrict__ Wk, const float* __restrict__ bk,
    const float* __restrict__ bv, const float* __restrict__ g1,
    const float* __restrict__ b1,
    const unsigned short* __restrict__ Wvf,
    float* __restrict__ qn, float* __restrict__ kn,
    unsigned short* __restrict__ knTh, unsigned short* __restrict__ knTl,
    float* __restrict__ knsq, float* __restrict__ vall)
{
    __shared__ __align__(16) char pool[19840];
    const int tid = threadIdx.x;
    const int bid = blockIdx.x;
    const int rem = bid % 3;

    if (rem != 2) {
        // ================= proj_qk path (R8 verbatim) =================
        const int qkidx = (bid / 3) * 2 + rem;
        float* ks = (float*)pool;                          // 8*128 floats
        float (*nred)[2]  = (float(*)[2])(pool + 4096);    // [8][2]
        float (*kred)[2]  = (float(*)[2])(pool + 4160);
        float (*k2red)[2] = (float(*)[2])(pool + 4224);

        const int b = qkidx & 7;
        const int chunk = qkidx >> 3;
        const size_t t0 = (size_t)b * SEQ + (size_t)chunk * 8;

        {
            const int col = tid & 127, half = tid >> 7;
            const int half_u = __builtin_amdgcn_readfirstlane(half);
            const float* xrow[4];
            #pragma unroll
            for (int t = 0; t < 4; ++t)
                xrow[t] = x + (t0 + (size_t)(half_u * 4 + t)) * DM;

            float qa[4] = {0.f, 0.f, 0.f, 0.f}, ka[4] = {0.f, 0.f, 0.f, 0.f};
            for (int d = 0; d < 256; d += 4) {
                float4 xv[4];
                #pragma unroll
                for (int t = 0; t < 4; ++t) xv[t] = *(const float4*)(xrow[t] + d);
                #pragma unroll
                for (int dd = 0; dd < 4; ++dd) {
                    float wq = Wq[(d + dd) * DQK + col];
                    float wk = Wk[(d + dd) * DQK + col];
                    #pragma unroll
                    for (int t = 0; t < 4; ++t) {
                        float xval = (dd == 0) ? xv[t].x : (dd == 1) ? xv[t].y
                                   : (dd == 2) ? xv[t].z : xv[t].w;
                        qa[t] = fmaf(xval, wq, qa[t]);
                        ka[t] = fmaf(xval, wk, ka[t]);
                    }
                }
            }
            #pragma unroll
            for (int t = 0; t < 4; ++t) { qa[t] += bq[col]; ka[t] += bk[col]; }

            const int sub = (tid >> 6) & 1;
            #pragma unroll
            for (int t = 0; t < 4; ++t) {
                float sq = qa[t] * qa[t], sk = ka[t] * ka[t];
                #pragma unroll
                for (int m = 1; m < 64; m <<= 1) { sq += __shfl_xor(sq, m); sk += __shfl_xor(sk, m); }
                if ((tid & 63) == 0) { nred[half * 4 + t][sub] = sq; kred[half * 4 + t][sub] = sk; }
            }
            __syncthreads();
            float kvv[4];
            #pragma unroll
            for (int t = 0; t < 4; ++t) {
                int tok = half * 4 + t;
                float nq = sqrtf(nred[tok][0] + nred[tok][1]);
                float nk = sqrtf(kred[tok][0] + kred[tok][1]);
                float qv = qa[t] / fmaxf(nq, 1e-12f);
                float kv = ka[t] / fmaxf(nk, 1e-12f);
                qn[(t0 + tok) * DQK + col] = qv;
                kn[(t0 + tok) * DQK + col] = kv;
                ks[tok * 128 + col] = kv;
                kvv[t] = kv;
            }
            #pragma unroll
            for (int t = 0; t < 4; ++t) {
                float s2 = kvv[t] * kvv[t];
                #pragma unroll
                for (int m = 1; m < 64; m <<= 1) s2 += __shfl_xor(s2, m);
                if ((tid & 63) == 0) k2red[half * 4 + t][sub] = s2;
            }
            __syncthreads();
            if (tid < 8) knsq[t0 + tid] = k2red[tid][0] + k2red[tid][1];
        }

        // --- K^T -> fp16 hi/lo B-fragments ---
        {
            const int e   = tid & 127;
            const int sel = tid >> 7;           // 0 = hi, 1 = lo(*4096)
            const int key = e & 7;
            const int kq  = e >> 3;             // kk*4 + qd
            const int kk  = kq >> 2, qd = kq & 3;
            const int nt  = chunk >> 1;
            const int n   = ((chunk & 1) << 3) + key;
            const float* src = &ks[key * 128 + kk * 32 + qd * 8];
            unsigned int pk[4];
            #pragma unroll
            for (int jj = 0; jj < 4; ++jj) {
                float v0 = src[2 * jj], v1 = src[2 * jj + 1];
                _Float16 h0 = (_Float16)v0, h1 = (_Float16)v1;
                unsigned short u0, u1;
                if (sel == 0) {
                    u0 = __builtin_bit_cast(unsigned short, h0);
                    u1 = __builtin_bit_cast(unsigned short, h1);
                } else {
                    _Float16 l0 = (_Float16)((v0 - (float)h0) * 4096.f);
                    _Float16 l1 = (_Float16)((v1 - (float)h1) * 4096.f);
                    u0 = __builtin_bit_cast(unsigned short, l0);
                    u1 = __builtin_bit_cast(unsigned short, l1);
                }
                pk[jj] = (unsigned int)u0 | ((unsigned int)u1 << 16);
            }
            unsigned short* dst = (sel ? knTl : knTh)
                + (size_t)b * 262144
                + (size_t)((nt * 4 + kk) * 64 + qd * 16 + n) * 8;
            *(uint4*)dst = make_uint4(pk[0], pk[1], pk[2], pk[3]);
        }
    } else {
        // ================= proj_v path (verbatim) =================
        float (*xs)[260] = (float(*)[260])pool;            // 16640B
        float* stat_m = (float*)(pool + 16640);            // 64B
        float* stat_r = (float*)(pool + 16704);            // 64B
        float* bvs = (float*)(pool + 16768);               // 1024B
        float* g1s = (float*)(pool + 17792);               // 1024B
        float* b1s = (float*)(pool + 18816);               // 1024B

        const int lane = tid & 63, wave = tid >> 6;
        const int quad = lane >> 4, lr = lane & 15;
        const size_t t0 = (size_t)(bid / 3) * 16;

        for (int i = tid; i < 16 * 256; i += 256) xs[i >> 8][i & 255] = x[t0 * DM + i];
        bvs[tid] = bv[tid]; g1s[tid] = g1[tid]; b1s[tid] = b1[tid];
        __syncthreads();

        {
            int tok = tid >> 4, l = tid & 15;
            float s = 0.f, s2 = 0.f;
            #pragma unroll
            for (int i = 0; i < 16; ++i) {
                float v = xs[tok][l + 16 * i];
                s += v; s2 += v * v;
            }
            #pragma unroll
            for (int m = 1; m < 16; m <<= 1) { s += __shfl_xor(s, m); s2 += __shfl_xor(s2, m); }
            if (l == 0) {
                float mean = s * (1.f / 256.f);
                float var  = s2 * (1.f / 256.f) - mean * mean;
                stat_m[tok] = mean;
                stat_r[tok] = rsqrtf(var + 1e-5f);
            }
        }
        __syncthreads();

        short8 av[8];
        {
            float mm = stat_m[lr], rr = stat_r[lr];
            #pragma unroll
            for (int kk = 0; kk < 8; ++kk) {
                #pragma unroll
                for (int j = 0; j < 8; ++j) {
                    int k = kk * 32 + quad * 8 + j;
                    float v = (xs[lr][k] - mm) * rr * g1s[k] + b1s[k];
                    av[kk][j] = (short)f2bf(v);
                }
            }
        }
        floatx4 acc[4];
        #pragma unroll
        for (int nt = 0; nt < 4; ++nt) acc[nt] = (floatx4){0.f, 0.f, 0.f, 0.f};
        #pragma unroll
        for (int nt = 0; nt < 4; ++nt) {
            #pragma unroll
            for (int kk = 0; kk < 8; ++kk) {
                short8 bfr = *(const short8*)(Wvf + ((size_t)(((wave * 4 + nt) * 8 + kk) * 64) + lane) * 8);
                acc[nt] = __builtin_amdgcn_mfma_f32_16x16x32_bf16(av[kk], bfr, acc[nt], 0, 0, 0);
            }
        }
        #pragma unroll
        for (int nt = 0; nt < 4; ++nt) {
            int col = (wave * 4 + nt) * 16 + lr;
            float bb = bvs[col];
            #pragma unroll
            for (int reg = 0; reg < 4; ++reg) {
                int row = quad * 4 + reg;
                vall[(t0 + row) * DM + col] = acc[nt][reg] + bb;
            }
        }
    }
}

// ---------------------------------------------------------------------------
// Kernel B: FUSED attn + ffn, 16 tokens/block (R13/R14 verbatim — 201us).
// ---------------------------------------------------------------------------
__global__ __launch_bounds__(256, 4) void attn_ffn_kernel(
    const float* __restrict__ x,
    const float* __restrict__ qn_g, const float* __restrict__ kn_g,
    const unsigned short* __restrict__ knTh, const unsigned short* __restrict__ knTl,
    const float* __restrict__ knsq_g,
    const float* __restrict__ vall,
    const unsigned short* __restrict__ Wof, const float* __restrict__ bo,
    const float* __restrict__ gf, const float* __restrict__ bf,
    const unsigned short* __restrict__ W1f, const float* __restrict__ b1f,
    const unsigned short* __restrict__ W2f, const float* __restrict__ b2f,
    const float* __restrict__ rw, float* __restrict__ out)
{
    __shared__ __align__(16) char pool[33024];
    __shared__ float stat_m[16], stat_r[16];
    float* s_ld   = (float*)pool;                       // 16x512 scores (32KB)
    float* attn_s = s_ld;                               // 16*128
    float* o8     = s_ld + 2048;                        // 16*260 (stride 260)
    float (*xs2)[260] = (float(*)[260])pool;            // 16640B (overlay)
    unsigned short* Af = (unsigned short*)(pool + 16640); // 8192B
    unsigned short (*G)[1032] = (unsigned short(*)[1032])pool; // 33024B (overlay)

    const int tid = threadIdx.x;
    const int lane = tid & 63, wave = tid >> 6;
    const int quad = lane >> 4, lr = lane & 15;
    const int sg = lane >> 5, sl = lane & 31;     // 32-lane subgroup
    const int sgid = wave * 2 + sg;               // 0..7
    const int b = blockIdx.x & 7;
    const int chunk = blockIdx.x >> 3;            // 0..127
    const size_t tq0 = (size_t)b * SEQ + (size_t)chunk * 16;
    const size_t rowb = (size_t)b * SEQ;

    half8 a_hi[4], a_lo[4];
    {
        const float* qrow = qn_g + (tq0 + lr) * DQK + quad * 8;
        #pragma unroll
        for (int kk = 0; kk < 4; ++kk) {
            float4 fa = *(const float4*)(qrow + kk * 32);
            float4 fb = *(const float4*)(qrow + kk * 32 + 4);
            float vv[8] = {fa.x, fa.y, fa.z, fa.w, fb.x, fb.y, fb.z, fb.w};
            #pragma unroll
            for (int j = 0; j < 8; ++j) {
                float v = vv[j];
                _Float16 h = (_Float16)v;
                a_hi[kk][j] = h;
                a_lo[kk][j] = (_Float16)((v - (float)h) * 4096.f);
            }
        }
    }

    const unsigned short* bh = knTh + (size_t)b * 262144;
    const unsigned short* bl = knTl + (size_t)b * 262144;
    const float* ksqb = knsq_g + rowb;

    ull c0[2], c1[2];          // candidate regs: lane sl holds ranks sl, sl+32

    for (int q4 = 0; q4 < 4; ++q4) {
        if (q4) __syncthreads();

        for (int t = 0; t < 8; ++t) {
            const int tile = q4 * 32 + wave * 8 + t;
            const unsigned short* ph = bh + (size_t)tile * 2048 + lane * 8;
            const unsigned short* pl = bl + (size_t)tile * 2048 + lane * 8;
            floatx4 am  = (floatx4){0.f, 0.f, 0.f, 0.f};
            floatx4 ax1 = (floatx4){0.f, 0.f, 0.f, 0.f};
            floatx4 ax2 = (floatx4){0.f, 0.f, 0.f, 0.f};
            #pragma unroll
            for (int kk = 0; kk < 4; ++kk) {
                half8 bhf = *(const half8*)(ph + kk * 512);
                half8 blf = *(const half8*)(pl + kk * 512);
                am  = __builtin_amdgcn_mfma_f32_16x16x32_f16(a_hi[kk], bhf, am,  0, 0, 0);
                ax1 = __builtin_amdgcn_mfma_f32_16x16x32_f16(a_hi[kk], blf, ax1, 0, 0, 0);
                ax2 = __builtin_amdgcn_mfma_f32_16x16x32_f16(a_lo[kk], bhf, ax2, 0, 0, 0);
            }
            const int keyloc = (wave * 8 + t) * 16 + lr;
            const float kq = ksqb[q4 * 512 + keyloc];
            #pragma unroll
            for (int r = 0; r < 4; ++r) {
                s_ld[(quad * 4 + r) * 512 + keyloc] =
                    2.f * (am[r] + (ax1[r] + ax2[r]) * (1.f / 4096.f)) - kq;
            }
        }
        __syncthreads();

        #pragma unroll
        for (int qi = 0; qi < 2; ++qi) {
            const int q = sgid + 8 * qi;
            const float* srow = &s_ld[q * 512 + sl];
            float f0 = -INFINITY, f1 = -INFINITY;
            int   i0 = 0, i1 = 0;
            #pragma unroll
            for (int i = 0; i < 16; ++i) {
                float f = srow[32 * i];
                int gidx = q4 * 512 + sl + 32 * i;
                bool a  = f > f0;
                bool bb = f > f1;
                f1 = a ? f0 : (bb ? f    : f1);
                i1 = a ? i0 : (bb ? gidx : i1);
                f0 = a ? f    : f0;
                i0 = a ? gidx : i0;
            }
            ull k2v = mkkey(f1, i1);
            ull cur = mkkey(f0, i0);
            int cnt = 0;
            for (int r = 0; r < NK; ++r) {
                ull w = cur;
                #pragma unroll
                for (int m = 1; m < 32; m <<= 1) {
                    ull o = shfl_xor_u64(w, m);
                    if (o > w) w = o;
                }
                const int slot = q4 * 16 + r;
                if (sl == slot)      c0[qi] = w;
                if (sl == slot - 32) c1[qi] = w;
                if (cur == w) {
                    ++cnt;
                    if (cnt == 1) cur = k2v;
                    else {
                        ull best = 0;
                        #pragma unroll
                        for (int i = 0; i < 16; ++i) {
                            float f = srow[32 * i];
                            ull k = mkkey(f, q4 * 512 + sl + 32 * i);
                            if (k < w && k > best) best = k;
                        }
                        cur = best;
                    }
                }
            }
        }
    }
    __syncthreads();

    int tidx[2] = {0, 0};
    #pragma unroll
    for (int qi = 0; qi < 2; ++qi) {
        ull ca = c0[qi], cb = c1[qi];
        ull hi = ca > cb ? ca : cb;
        ull lo = ca > cb ? cb : ca;
        ull cur = hi;
        int cnt = 0;
        for (int r = 0; r < NK; ++r) {
            ull w = cur;
            #pragma unroll
            for (int m = 1; m < 32; m <<= 1) {
                ull o = shfl_xor_u64(w, m);
                if (o > w) w = o;
            }
            if (sl == r) tidx[qi] = 2047 - (int)(unsigned int)(w & 0xFFFFFFFFull);
            if (cur == w) { ++cnt; cur = (cnt == 1) ? lo : 0ull; }
        }
    }

    #pragma unroll
    for (int qq = 0; qq < 4; ++qq) {
        const int sgq = qq & 1;
        const int qiq = qq >> 1;
        const int q   = wave * 2 + sgq + 8 * qiq;
        const int srcb = sgq * 32;
        const int h = lane >> 3;
        const int k1 = lane & 7, k2 = 8 + (lane & 7);
        const int i1 = __shfl(tidx[qiq], srcb + k1);
        const int i2 = __shfl(tidx[qiq], srcb + k2);
        const float* qrow = qn_g + (tq0 + q) * DQK + h * 16;
        const float* kr1 = kn_g + (rowb + i1) * DQK + h * 16;
        const float* kr2 = kn_g + (rowb + i2) * DQK + h * 16;
        float lg1 = 0.f, lg2 = 0.f;
        #pragma unroll
        for (int d = 0; d < 16; d += 4) {
            float4 qv = *(const float4*)&qrow[d];
            float4 a1 = *(const float4*)&kr1[d];
            float4 a2 = *(const float4*)&kr2[d];
            lg1 = fmaf(qv.x, a1.x, lg1); lg1 = fmaf(qv.y, a1.y, lg1);
            lg1 = fmaf(qv.z, a1.z, lg1); lg1 = fmaf(qv.w, a1.w, lg1);
            lg2 = fmaf(qv.x, a2.x, lg2); lg2 = fmaf(qv.y, a2.y, lg2);
            lg2 = fmaf(qv.z, a2.z, lg2); lg2 = fmaf(qv.w, a2.w, lg2);
        }
        lg1 *= 0.25f; lg2 *= 0.25f;
        float mx = fmaxf(lg1, lg2);
        #pragma unroll
        for (int m = 1; m < 8; m <<= 1) mx = fmaxf(mx, __shfl_xor(mx, m));
        float e1 = expf(lg1 - mx), e2 = expf(lg2 - mx);
        float ssum = e1 + e2;
        #pragma unroll
        for (int m = 1; m < 8; m <<= 1) ssum += __shfl_xor(ssum, m);
        attn_s[q * 128 + h * 16 + k1] = e1 / ssum;
        attn_s[q * 128 + h * 16 + k2] = e2 / ssum;
        // within-wave LDS RAW: ordered by lgkmcnt, no barrier needed

        float o[4] = {0.f, 0.f, 0.f, 0.f};
        for (int k = 0; k < NK; ++k) {
            const int ik = __shfl(tidx[qiq], srcb + k);
            const float* vr = vall + (rowb + ik) * DM;
            #pragma unroll
            for (int j = 0; j < 4; ++j) {
                int d = lane + 64 * j;
                o[j] = fmaf(attn_s[q * 128 + (d >> 5) * 16 + k], vr[d], o[j]);
            }
        }
        #pragma unroll
        for (int j = 0; j < 4; ++j) o8[q * 260 + lane + 64 * j] = o[j];
    }
    __syncthreads();    // o8 is read cross-wave in the Wo phase

    // ---- Wo via bf16 MFMA; outputs stay in registers (oval) ----
    float rwv = rw[0];
    float oval[4][4];
    {
        short8 ao[8];
        #pragma unroll
        for (int kk = 0; kk < 8; ++kk) {
            #pragma unroll
            for (int j = 0; j < 8; ++j) {
                int k = kk * 32 + quad * 8 + j;
                ao[kk][j] = (short)f2bf(o8[lr * 260 + k]);
            }
        }
        __syncthreads();    // all o8 reads done; xs2 may overlay pool below
        floatx4 aw[4];
        #pragma unroll
        for (int nt = 0; nt < 4; ++nt) aw[nt] = (floatx4){0.f, 0.f, 0.f, 0.f};
        #pragma unroll
        for (int nt = 0; nt < 4; ++nt) {
            #pragma unroll
            for (int kk = 0; kk < 8; ++kk) {
                short8 bofr = *(const short8*)(Wof + ((size_t)(((wave * 4 + nt) * 8 + kk) * 64) + lane) * 8);
                aw[nt] = __builtin_amdgcn_mfma_f32_16x16x32_bf16(ao[kk], bofr, aw[nt], 0, 0, 0);
            }
        }
        #pragma unroll
        for (int nt = 0; nt < 4; ++nt) {
            int col = (wave * 4 + nt) * 16 + lr;
            float bov = bo[col];
            #pragma unroll
            for (int reg = 0; reg < 4; ++reg) {
                int row = quad * 4 + reg;
                float v = x[(tq0 + row) * DM + col] + (aw[nt][reg] + bov) * rwv;
                oval[nt][reg] = v;
                xs2[row][col] = v;            // stage for LN / fragments
            }
        }
    }
    __syncthreads();    // xs2 complete (cross-wave reads follow)

    // ---- FFN phase (16 tokens) — math identical to standalone ffn ----
    {
        int tok = tid >> 4, l = tid & 15;
        float s = 0.f, s2 = 0.f;
        #pragma unroll
        for (int i = 0; i < 16; ++i) {
            float v = xs2[tok][l + 16 * i];
            s += v; s2 += v * v;
        }
        #pragma unroll
        for (int m = 1; m < 16; m <<= 1) { s += __shfl_xor(s, m); s2 += __shfl_xor(s2, m); }
        if (l == 0) {
            float mean = s * (1.f / 256.f);
            float var  = s2 * (1.f / 256.f) - mean * mean;
            stat_m[tok] = mean;
            stat_r[tok] = rsqrtf(var + 1e-5f);
        }
    }
    __syncthreads();

    // A-fragments (rows 0..15): wave handles kk = wave, wave+4
    for (int kk = wave; kk < 8; kk += 4) {
        int m = lr, k0 = kk * 32 + quad * 8;
        float mm = stat_m[m], rr = stat_r[m];
        unsigned int pk[4];
        #pragma unroll
        for (int jj = 0; jj < 4; ++jj) {
            int ka = k0 + 2 * jj, kb = ka + 1;
            float v0 = (xs2[m][ka] - mm) * rr * gf[ka] + bf[ka];
            float v1 = (xs2[m][kb] - mm) * rr * gf[kb] + bf[kb];
            pk[jj] = (unsigned int)f2bf(v0) | ((unsigned int)f2bf(v1) << 16);
        }
        *(uint4*)&Af[(kk * 64 + lane) * 8] = make_uint4(pk[0], pk[1], pk[2], pk[3]);
    }
    __syncthreads();

    short8 afr[8];
    #pragma unroll
    for (int kk = 0; kk < 8; ++kk)
        afr[kk] = *(const short8*)&Af[(kk * 64 + lane) * 8];
    __syncthreads();    // xs2/Af reads done before G overlays the pool

    // GEMM1: wave owns col-tiles ntg = wave*16+nt, nt=0..15
    for (int nt = 0; nt < 16; ++nt) {
        floatx4 acc = (floatx4){0.f, 0.f, 0.f, 0.f};
        const int ntg = wave * 16 + nt;
        #pragma unroll
        for (int kk = 0; kk < 8; ++kk) {
            short8 bfr = *(const short8*)(W1f + (size_t)((ntg * 8 + kk) * 64 + lane) * 8);
            acc = __builtin_amdgcn_mfma_f32_16x16x32_bf16(afr[kk], bfr, acc, 0, 0, 0);
        }
        const int n = ntg * 16 + lr;
        const float bb = b1f[n];
        #pragma unroll
        for (int reg = 0; reg < 4; ++reg) {
            int row = quad * 4 + reg;
            G[row][n] = f2bf(gelu_fast(acc[reg] + bb));
        }
    }
    __syncthreads();

    // GEMM2: wave owns col-tiles ct = wave*4+nt2, nt2=0..3
    floatx4 acc2[4];
    #pragma unroll
    for (int nt2 = 0; nt2 < 4; ++nt2) acc2[nt2] = (floatx4){0.f, 0.f, 0.f, 0.f};
    for (int kk2 = 0; kk2 < 32; ++kk2) {
        short8 a2 = *(const short8*)&G[lr][kk2 * 32 + quad * 8];
        #pragma unroll
        for (int nt2 = 0; nt2 < 4; ++nt2) {
            short8 b2 = *(const short8*)(W2f + (size_t)((((wave * 4 + nt2) * 32 + kk2) * 64 + lane) * 8));
            acc2[nt2] = __builtin_amdgcn_mfma_f32_16x16x32_bf16(a2, b2, acc2[nt2], 0, 0, 0);
        }
    }

    #pragma unroll
    for (int nt2 = 0; nt2 < 4; ++nt2) {
        int col = (wave * 4 + nt2) * 16 + lr;
        float bb = b2f[col];
        #pragma unroll
        for (int reg = 0; reg < 4; ++reg) {
            int row = quad * 4 + reg;
            float o = acc2[nt2][reg] + bb;
            out[(tq0 + row) * DM + col] = oval[nt2][reg] + o * rwv;
        }
    }
}

// ---------------------------------------------------------------------------
extern "C" void kernel_launch(void* const* d_in, const int* in_sizes, int n_in,
                              void* d_out, int out_size, void* d_ws, size_t ws_size,
                              hipStream_t stream)
{
    const float* x   = (const float*)d_in[0];
    const float* Wq  = (const float*)d_in[1];
    const float* bq  = (const float*)d_in[2];
    const float* Wk  = (const float*)d_in[3];
    const float* bk  = (const float*)d_in[4];
    const float* Wv  = (const float*)d_in[5];
    const float* bv  = (const float*)d_in[6];
    const float* Wo  = (const float*)d_in[7];
    const float* bo  = (const float*)d_in[8];
    const float* g1  = (const float*)d_in[9];
    const float* b1  = (const float*)d_in[10];
    const float* gf  = (const float*)d_in[11];
    const float* bf  = (const float*)d_in[12];
    const float* W1  = (const float*)d_in[13];
    const float* b1f = (const float*)d_in[14];
    const float* W2  = (const float*)d_in[15];
    const float* b2f = (const float*)d_in[16];
    const float* rw  = (const float*)d_in[17];
    float* out = (float*)d_out;

    // workspace (~43.3 MB): qn | kn | knTh/knTl | vall | knsq | W1f | W2f | Wvf | Wof
    float* ws   = (float*)d_ws;
    float* qn   = ws;                          // 2,097,152 floats
    float* kn   = ws + 2097152;                // 2,097,152
    unsigned short* knTh = (unsigned short*)(ws + 4194304);  // 2,097,152 shorts (4MB)
    unsigned short* knTl = knTh + 2097152;                   // 2,097,152 shorts (4MB)
    float* vall = ws + 6291456;                // 4,194,304
    float* knsq = ws + 10485760;               // 16,384
    unsigned short* W1f = (unsigned short*)(ws + 10502144);   // 262,144 shorts
    unsigned short* W2f = W1f + 262144;                       // 262,144
    unsigned short* Wvf = W2f + 262144;                       // 65,536
    unsigned short* Wof = Wvf + 65536;                        // 65,536

    conv_kernel<<<320, 256, 0, stream>>>(W1, W2, Wv, Wo, W1f, W2f, Wvf, Wof);
    proj_merged_kernel<<<3072, 256, 0, stream>>>(
        x, Wq, bq, Wk, bk, bv, g1, b1, Wvf,
        qn, kn, knTh, knTl, knsq, vall);
    attn_ffn_kernel<<<BATCH * SEQ / 16, 256, 0, stream>>>(
        x, qn, kn, knTh, knTl, knsq, vall, Wof, bo,
        gf, bf, W1f, b1f, W2f, b2f, rw, out);
}

// Round 16
// 326.449 us; speedup vs baseline: 1.0303x; 1.0303x over previous
//
#include <hip/hip_runtime.h>
#include <math.h>

#define BATCH 8
#define SEQ   2048
#define DM    256
#define DQK   128
#define NHEADS 8
#define NK    16
#define DFF   1024

typedef __attribute__((ext_vector_type(8))) short short8;
typedef __attribute__((ext_vector_type(8))) _Float16 half8;
typedef __attribute__((ext_vector_type(4))) float floatx4;
typedef unsigned long long ull;

__device__ __forceinline__ unsigned short f2bf(float f) {
    unsigned int u = __float_as_uint(f);
    u += 0x7fffu + ((u >> 16) & 1u);          // round-to-nearest-even
    return (unsigned short)(u >> 16);
}

__device__ __forceinline__ float gelu_fast(float h) {
    float y = 0.7978845608028654f * (h + 0.044715f * h * h * h);
    float e = __expf(2.f * y);
    float t = 1.f - 2.f / (e + 1.f);
    return 0.5f * h * (1.f + t);
}

// composite sort key: primary score desc, secondary idx asc. Unique per idx.
__device__ __forceinline__ ull mkkey(float f, int gidx) {
    unsigned int u = __float_as_uint(f);
    u ^= (unsigned int)((int)u >> 31) | 0x80000000u;   // sortable float
    return ((ull)u << 32) | (unsigned int)(2047 - gidx);
}

__device__ __forceinline__ ull shfl_xor_u64(ull v, int m) {
    unsigned int lo = (unsigned int)v, hi = (unsigned int)(v >> 32);
    lo = __shfl_xor(lo, m);
    hi = __shfl_xor(hi, m);
    return ((ull)hi << 32) | lo;
}

// ---------------------------------------------------------------------------
// Kernel W: repack W1/W2/Wv/Wo fp32 -> bf16 MFMA B-fragment order (verbatim).
// ---------------------------------------------------------------------------
__global__ __launch_bounds__(256) void conv_kernel(
    const float* __restrict__ W1, const float* __restrict__ W2,
    const float* __restrict__ Wv, const float* __restrict__ Wo,
    unsigned short* __restrict__ W1f, unsigned short* __restrict__ W2f,
    unsigned short* __restrict__ Wvf, unsigned short* __restrict__ Wof)
{
    int g = blockIdx.x * 256 + threadIdx.x;
    const float* W; unsigned short* O; int e, stride;
    if (g < 32768)      { W = W1; O = W1f; e = g;         stride = DFF; }
    else if (g < 65536) { W = W2; O = W2f; e = g - 32768; stride = DM;  }
    else if (g < 73728) { W = Wv; O = Wvf; e = g - 65536; stride = DM;  }
    else                { W = Wo; O = Wof; e = g - 73728; stride = DM;  }
    int lane = e & 63;
    int kk, nt;
    if (g < 32768)      { kk = (e >> 6) & 7;  nt = e >> 9;  }
    else if (g < 65536) { kk = (e >> 6) & 31; nt = e >> 11; }
    else                { kk = (e >> 6) & 7;  nt = e >> 9;  }
    int n = nt * 16 + (lane & 15);
    int k0 = kk * 32 + (lane >> 4) * 8;
    unsigned int pk[4];
    #pragma unroll
    for (int jj = 0; jj < 4; ++jj) {
        unsigned short lo = f2bf(W[(size_t)(k0 + 2 * jj) * stride + n]);
        unsigned short hi = f2bf(W[(size_t)(k0 + 2 * jj + 1) * stride + n]);
        pk[jj] = (unsigned int)lo | ((unsigned int)hi << 16);
    }
    *(uint4*)(O + (size_t)e * 8) = make_uint4(pk[0], pk[1], pk[2], pk[3]);
}

// ---------------------------------------------------------------------------
// Kernel P: MERGED projections (R14-measured: range split). Blocks 0..2047
// run the proj_qk path (R8 verbatim); blocks 2048..3071 run the proj_v
// path (verbatim). Shared memory = union pool -> 8 blocks/CU.
// ---------------------------------------------------------------------------
__global__ __launch_bounds__(256) void proj_merged_kernel(
    const float* __restrict__ x,
    const float* __restrict__ Wq, const float* __restrict__ bq,
    const float* __restrict__ Wk, const float* __restrict__ bk,
    const float* __restrict__ bv, const float* __restrict__ g1,
    const float* __restrict__ b1,
    const unsigned short* __restrict__ Wvf,
    float* __restrict__ qn, float* __restrict__ kn,
    unsigned short* __restrict__ knTh, unsigned short* __restrict__ knTl,
    float* __restrict__ knsq, float* __restrict__ vall)
{
    __shared__ __align__(16) char pool[19840];
    const int tid = threadIdx.x;

    if (blockIdx.x < 2048) {
        // ================= proj_qk path (R8 verbatim) =================
        float* ks = (float*)pool;                          // 8*128 floats
        float (*nred)[2]  = (float(*)[2])(pool + 4096);    // [8][2]
        float (*kred)[2]  = (float(*)[2])(pool + 4160);
        float (*k2red)[2] = (float(*)[2])(pool + 4224);

        const int b = blockIdx.x & 7;
        const int chunk = blockIdx.x >> 3;
        const size_t t0 = (size_t)b * SEQ + (size_t)chunk * 8;

        {
            const int col = tid & 127, half = tid >> 7;
            const int half_u = __builtin_amdgcn_readfirstlane(half);
            const float* xrow[4];
            #pragma unroll
            for (int t = 0; t < 4; ++t)
                xrow[t] = x + (t0 + (size_t)(half_u * 4 + t)) * DM;

            float qa[4] = {0.f, 0.f, 0.f, 0.f}, ka[4] = {0.f, 0.f, 0.f, 0.f};
            for (int d = 0; d < 256; d += 4) {
                float4 xv[4];
                #pragma unroll
                for (int t = 0; t < 4; ++t) xv[t] = *(const float4*)(xrow[t] + d);
                #pragma unroll
                for (int dd = 0; dd < 4; ++dd) {
                    float wq = Wq[(d + dd) * DQK + col];
                    float wk = Wk[(d + dd) * DQK + col];
                    #pragma unroll
                    for (int t = 0; t < 4; ++t) {
                        float xval = (dd == 0) ? xv[t].x : (dd == 1) ? xv[t].y
                                   : (dd == 2) ? xv[t].z : xv[t].w;
                        qa[t] = fmaf(xval, wq, qa[t]);
                        ka[t] = fmaf(xval, wk, ka[t]);
                    }
                }
            }
            #pragma unroll
            for (int t = 0; t < 4; ++t) { qa[t] += bq[col]; ka[t] += bk[col]; }

            const int sub = (tid >> 6) & 1;
            #pragma unroll
            for (int t = 0; t < 4; ++t) {
                float sq = qa[t] * qa[t], sk = ka[t] * ka[t];
                #pragma unroll
                for (int m = 1; m < 64; m <<= 1) { sq += __shfl_xor(sq, m); sk += __shfl_xor(sk, m); }
                if ((tid & 63) == 0) { nred[half * 4 + t][sub] = sq; kred[half * 4 + t][sub] = sk; }
            }
            __syncthreads();
            float kvv[4];
            #pragma unroll
            for (int t = 0; t < 4; ++t) {
                int tok = half * 4 + t;
                float nq = sqrtf(nred[tok][0] + nred[tok][1]);
                float nk = sqrtf(kred[tok][0] + kred[tok][1]);
                float qv = qa[t] / fmaxf(nq, 1e-12f);
                float kv = ka[t] / fmaxf(nk, 1e-12f);
                qn[(t0 + tok) * DQK + col] = qv;
                kn[(t0 + tok) * DQK + col] = kv;
                ks[tok * 128 + col] = kv;
                kvv[t] = kv;
            }
            #pragma unroll
            for (int t = 0; t < 4; ++t) {
                float s2 = kvv[t] * kvv[t];
                #pragma unroll
                for (int m = 1; m < 64; m <<= 1) s2 += __shfl_xor(s2, m);
                if ((tid & 63) == 0) k2red[half * 4 + t][sub] = s2;
            }
            __syncthreads();
            if (tid < 8) knsq[t0 + tid] = k2red[tid][0] + k2red[tid][1];
        }

        // --- K^T -> fp16 hi/lo B-fragments ---
        {
            const int e   = tid & 127;
            const int sel = tid >> 7;           // 0 = hi, 1 = lo(*4096)
            const int key = e & 7;
            const int kq  = e >> 3;             // kk*4 + qd
            const int kk  = kq >> 2, qd = kq & 3;
            const int nt  = chunk >> 1;
            const int n   = ((chunk & 1) << 3) + key;
            const float* src = &ks[key * 128 + kk * 32 + qd * 8];
            unsigned int pk[4];
            #pragma unroll
            for (int jj = 0; jj < 4; ++jj) {
                float v0 = src[2 * jj], v1 = src[2 * jj + 1];
                _Float16 h0 = (_Float16)v0, h1 = (_Float16)v1;
                unsigned short u0, u1;
                if (sel == 0) {
                    u0 = __builtin_bit_cast(unsigned short, h0);
                    u1 = __builtin_bit_cast(unsigned short, h1);
                } else {
                    _Float16 l0 = (_Float16)((v0 - (float)h0) * 4096.f);
                    _Float16 l1 = (_Float16)((v1 - (float)h1) * 4096.f);
                    u0 = __builtin_bit_cast(unsigned short, l0);
                    u1 = __builtin_bit_cast(unsigned short, l1);
                }
                pk[jj] = (unsigned int)u0 | ((unsigned int)u1 << 16);
            }
            unsigned short* dst = (sel ? knTl : knTh)
                + (size_t)b * 262144
                + (size_t)((nt * 4 + kk) * 64 + qd * 16 + n) * 8;
            *(uint4*)dst = make_uint4(pk[0], pk[1], pk[2], pk[3]);
        }
    } else {
        // ================= proj_v path (verbatim) =================
        float (*xs)[260] = (float(*)[260])pool;            // 16640B
        float* stat_m = (float*)(pool + 16640);            // 64B
        float* stat_r = (float*)(pool + 16704);            // 64B
        float* bvs = (float*)(pool + 16768);               // 1024B
        float* g1s = (float*)(pool + 17792);               // 1024B
        float* b1s = (float*)(pool + 18816);               // 1024B

        const int lane = tid & 63, wave = tid >> 6;
        const int quad = lane >> 4, lr = lane & 15;
        const size_t t0 = (size_t)(blockIdx.x - 2048) * 16;

        for (int i = tid; i < 16 * 256; i += 256) xs[i >> 8][i & 255] = x[t0 * DM + i];
        bvs[tid] = bv[tid]; g1s[tid] = g1[tid]; b1s[tid] = b1[tid];
        __syncthreads();

        {
            int tok = tid >> 4, l = tid & 15;
            float s = 0.f, s2 = 0.f;
            #pragma unroll
            for (int i = 0; i < 16; ++i) {
                float v = xs[tok][l + 16 * i];
                s += v; s2 += v * v;
            }
            #pragma unroll
            for (int m = 1; m < 16; m <<= 1) { s += __shfl_xor(s, m); s2 += __shfl_xor(s2, m); }
            if (l == 0) {
                float mean = s * (1.f / 256.f);
                float var  = s2 * (1.f / 256.f) - mean * mean;
                stat_m[tok] = mean;
                stat_r[tok] = rsqrtf(var + 1e-5f);
            }
        }
        __syncthreads();

        short8 av[8];
        {
            float mm = stat_m[lr], rr = stat_r[lr];
            #pragma unroll
            for (int kk = 0; kk < 8; ++kk) {
                #pragma unroll
                for (int j = 0; j < 8; ++j) {
                    int k = kk * 32 + quad * 8 + j;
                    float v = (xs[lr][k] - mm) * rr * g1s[k] + b1s[k];
                    av[kk][j] = (short)f2bf(v);
                }
            }
        }
        floatx4 acc[4];
        #pragma unroll
        for (int nt = 0; nt < 4; ++nt) acc[nt] = (floatx4){0.f, 0.f, 0.f, 0.f};
        #pragma unroll
        for (int nt = 0; nt < 4; ++nt) {
            #pragma unroll
            for (int kk = 0; kk < 8; ++kk) {
                short8 bfr = *(const short8*)(Wvf + ((size_t)(((wave * 4 + nt) * 8 + kk) * 64) + lane) * 8);
                acc[nt] = __builtin_amdgcn_mfma_f32_16x16x32_bf16(av[kk], bfr, acc[nt], 0, 0, 0);
            }
        }
        #pragma unroll
        for (int nt = 0; nt < 4; ++nt) {
            int col = (wave * 4 + nt) * 16 + lr;
            float bb = bvs[col];
            #pragma unroll
            for (int reg = 0; reg < 4; ++reg) {
                int row = quad * 4 + reg;
                vall[(t0 + row) * DM + col] = acc[nt][reg] + bb;
            }
        }
    }
}

// ---------------------------------------------------------------------------
// Kernel B: FUSED attn + ffn, 16 tokens/block (R13/R14 verbatim — 201us).
// ---------------------------------------------------------------------------
__global__ __launch_bounds__(256, 4) void attn_ffn_kernel(
    const float* __restrict__ x,
    const float* __restrict__ qn_g, const float* __restrict__ kn_g,
    const unsigned short* __restrict__ knTh, const unsigned short* __restrict__ knTl,
    const float* __restrict__ knsq_g,
    const float* __restrict__ vall,
    const unsigned short* __restrict__ Wof, const float* __restrict__ bo,
    const float* __restrict__ gf, const float* __restrict__ bf,
    const unsigned short* __restrict__ W1f, const float* __restrict__ b1f,
    const unsigned short* __restrict__ W2f, const float* __restrict__ b2f,
    const float* __restrict__ rw, float* __restrict__ out)
{
    __shared__ __align__(16) char pool[33024];
    __shared__ float stat_m[16], stat_r[16];
    float* s_ld   = (float*)pool;                       // 16x512 scores (32KB)
    float* attn_s = s_ld;                               // 16*128
    float* o8     = s_ld + 2048;                        // 16*260 (stride 260)
    float (*xs2)[260] = (float(*)[260])pool;            // 16640B (overlay)
    unsigned short* Af = (unsigned short*)(pool + 16640); // 8192B
    unsigned short (*G)[1032] = (unsigned short(*)[1032])pool; // 33024B (overlay)

    const int tid = threadIdx.x;
    const int lane = tid & 63, wave = tid >> 6;
    const int quad = lane >> 4, lr = lane & 15;
    const int sg = lane >> 5, sl = lane & 31;     // 32-lane subgroup
    const int sgid = wave * 2 + sg;               // 0..7
    const int b = blockIdx.x & 7;
    const int chunk = blockIdx.x >> 3;            // 0..127
    const size_t tq0 = (size_t)b * SEQ + (size_t)chunk * 16;
    const size_t rowb = (size_t)b * SEQ;

    half8 a_hi[4], a_lo[4];
    {
        const float* qrow = qn_g + (tq0 + lr) * DQK + quad * 8;
        #pragma unroll
        for (int kk = 0; kk < 4; ++kk) {
            float4 fa = *(const float4*)(qrow + kk * 32);
            float4 fb = *(const float4*)(qrow + kk * 32 + 4);
            float vv[8] = {fa.x, fa.y, fa.z, fa.w, fb.x, fb.y, fb.z, fb.w};
            #pragma unroll
            for (int j = 0; j < 8; ++j) {
                float v = vv[j];
                _Float16 h = (_Float16)v;
                a_hi[kk][j] = h;
                a_lo[kk][j] = (_Float16)((v - (float)h) * 4096.f);
            }
        }
    }

    const unsigned short* bh = knTh + (size_t)b * 262144;
    const unsigned short* bl = knTl + (size_t)b * 262144;
    const float* ksqb = knsq_g + rowb;

    ull c0[2], c1[2];          // candidate regs: lane sl holds ranks sl, sl+32

    for (int q4 = 0; q4 < 4; ++q4) {
        if (q4) __syncthreads();

        for (int t = 0; t < 8; ++t) {
            const int tile = q4 * 32 + wave * 8 + t;
            const unsigned short* ph = bh + (size_t)tile * 2048 + lane * 8;
            const unsigned short* pl = bl + (size_t)tile * 2048 + lane * 8;
            floatx4 am  = (floatx4){0.f, 0.f, 0.f, 0.f};
            floatx4 ax1 = (floatx4){0.f, 0.f, 0.f, 0.f};
            floatx4 ax2 = (floatx4){0.f, 0.f, 0.f, 0.f};
            #pragma unroll
            for (int kk = 0; kk < 4; ++kk) {
                half8 bhf = *(const half8*)(ph + kk * 512);
                half8 blf = *(const half8*)(pl + kk * 512);
                am  = __builtin_amdgcn_mfma_f32_16x16x32_f16(a_hi[kk], bhf, am,  0, 0, 0);
                ax1 = __builtin_amdgcn_mfma_f32_16x16x32_f16(a_hi[kk], blf, ax1, 0, 0, 0);
                ax2 = __builtin_amdgcn_mfma_f32_16x16x32_f16(a_lo[kk], bhf, ax2, 0, 0, 0);
            }
            const int keyloc = (wave * 8 + t) * 16 + lr;
            const float kq = ksqb[q4 * 512 + keyloc];
            #pragma unroll
            for (int r = 0; r < 4; ++r) {
                s_ld[(quad * 4 + r) * 512 + keyloc] =
                    2.f * (am[r] + (ax1[r] + ax2[r]) * (1.f / 4096.f)) - kq;
            }
        }
        __syncthreads();

        #pragma unroll
        for (int qi = 0; qi < 2; ++qi) {
            const int q = sgid + 8 * qi;
            const float* srow = &s_ld[q * 512 + sl];
            float f0 = -INFINITY, f1 = -INFINITY;
            int   i0 = 0, i1 = 0;
            #pragma unroll
            for (int i = 0; i < 16; ++i) {
                float f = srow[32 * i];
                int gidx = q4 * 512 + sl + 32 * i;
                bool a  = f > f0;
                bool bb = f > f1;
                f1 = a ? f0 : (bb ? f    : f1);
                i1 = a ? i0 : (bb ? gidx : i1);
                f0 = a ? f    : f0;
                i0 = a ? gidx : i0;
            }
            ull k2v = mkkey(f1, i1);
            ull cur = mkkey(f0, i0);
            int cnt = 0;
            for (int r = 0; r < NK; ++r) {
                ull w = cur;
                #pragma unroll
                for (int m = 1; m < 32; m <<= 1) {
                    ull o = shfl_xor_u64(w, m);
                    if (o > w) w = o;
                }
                const int slot = q4 * 16 + r;
                if (sl == slot)      c0[qi] = w;
                if (sl == slot - 32) c1[qi] = w;
                if (cur == w) {
                    ++cnt;
                    if (cnt == 1) cur = k2v;
                    else {
                        ull best = 0;
                        #pragma unroll
                        for (int i = 0; i < 16; ++i) {
                            float f = srow[32 * i];
                            ull k = mkkey(f, q4 * 512 + sl + 32 * i);
                            if (k < w && k > best) best = k;
                        }
                        cur = best;
                    }
                }
            }
        }
    }
    __syncthreads();

    int tidx[2] = {0, 0};
    #pragma unroll
    for (int qi = 0; qi < 2; ++qi) {
        ull ca = c0[qi], cb = c1[qi];
        ull hi = ca > cb ? ca : cb;
        ull lo = ca > cb ? cb : ca;
        ull cur = hi;
        int cnt = 0;
        for (int r = 0; r < NK; ++r) {
            ull w = cur;
            #pragma unroll
            for (int m = 1; m < 32; m <<= 1) {
                ull o = shfl_xor_u64(w, m);
                if (o > w) w = o;
            }
            if (sl == r) tidx[qi] = 2047 - (int)(unsigned int)(w & 0xFFFFFFFFull);
            if (cur == w) { ++cnt; cur = (cnt == 1) ? lo : 0ull; }
        }
    }

    #pragma unroll
    for (int qq = 0; qq < 4; ++qq) {
        const int sgq = qq & 1;
        const int qiq = qq >> 1;
        const int q   = wave * 2 + sgq + 8 * qiq;
        const int srcb = sgq * 32;
        const int h = lane >> 3;
        const int k1 = lane & 7, k2 = 8 + (lane & 7);
        const int i1 = __shfl(tidx[qiq], srcb + k1);
        const int i2 = __shfl(tidx[qiq], srcb + k2);
        const float* qrow = qn_g + (tq0 + q) * DQK + h * 16;
        const float* kr1 = kn_g + (rowb + i1) * DQK + h * 16;
        const float* kr2 = kn_g + (rowb + i2) * DQK + h * 16;
        float lg1 = 0.f, lg2 = 0.f;
        #pragma unroll
        for (int d = 0; d < 16; d += 4) {
            float4 qv = *(const float4*)&qrow[d];
            float4 a1 = *(const float4*)&kr1[d];
            float4 a2 = *(const float4*)&kr2[d];
            lg1 = fmaf(qv.x, a1.x, lg1); lg1 = fmaf(qv.y, a1.y, lg1);
            lg1 = fmaf(qv.z, a1.z, lg1); lg1 = fmaf(qv.w, a1.w, lg1);
            lg2 = fmaf(qv.x, a2.x, lg2); lg2 = fmaf(qv.y, a2.y, lg2);
            lg2 = fmaf(qv.z, a2.z, lg2); lg2 = fmaf(qv.w, a2.w, lg2);
        }
        lg1 *= 0.25f; lg2 *= 0.25f;
        float mx = fmaxf(lg1, lg2);
        #pragma unroll
        for (int m = 1; m < 8; m <<= 1) mx = fmaxf(mx, __shfl_xor(mx, m));
        float e1 = expf(lg1 - mx), e2 = expf(lg2 - mx);
        float ssum = e1 + e2;
        #pragma unroll
        for (int m = 1; m < 8; m <<= 1) ssum += __shfl_xor(ssum, m);
        attn_s[q * 128 + h * 16 + k1] = e1 / ssum;
        attn_s[q * 128 + h * 16 + k2] = e2 / ssum;
        // within-wave LDS RAW: ordered by lgkmcnt, no barrier needed

        float o[4] = {0.f, 0.f, 0.f, 0.f};
        for (int k = 0; k < NK; ++k) {
            const int ik = __shfl(tidx[qiq], srcb + k);
            const float* vr = vall + (rowb + ik) * DM;
            #pragma unroll
            for (int j = 0; j < 4; ++j) {
                int d = lane + 64 * j;
                o[j] = fmaf(attn_s[q * 128 + (d >> 5) * 16 + k], vr[d], o[j]);
            }
        }
        #pragma unroll
        for (int j = 0; j < 4; ++j) o8[q * 260 + lane + 64 * j] = o[j];
    }
    __syncthreads();    // o8 is read cross-wave in the Wo phase

    // ---- Wo via bf16 MFMA; outputs stay in registers (oval) ----
    float rwv = rw[0];
    float oval[4][4];
    {
        short8 ao[8];
        #pragma unroll
        for (int kk = 0; kk < 8; ++kk) {
            #pragma unroll
            for (int j = 0; j < 8; ++j) {
                int k = kk * 32 + quad * 8 + j;
                ao[kk][j] = (short)f2bf(o8[lr * 260 + k]);
            }
        }
        __syncthreads();    // all o8 reads done; xs2 may overlay pool below
        floatx4 aw[4];
        #pragma unroll
        for (int nt = 0; nt < 4; ++nt) aw[nt] = (floatx4){0.f, 0.f, 0.f, 0.f};
        #pragma unroll
        for (int nt = 0; nt < 4; ++nt) {
            #pragma unroll
            for (int kk = 0; kk < 8; ++kk) {
                short8 bofr = *(const short8*)(Wof + ((size_t)(((wave * 4 + nt) * 8 + kk) * 64) + lane) * 8);
                aw[nt] = __builtin_amdgcn_mfma_f32_16x16x32_bf16(ao[kk], bofr, aw[nt], 0, 0, 0);
            }
        }
        #pragma unroll
        for (int nt = 0; nt < 4; ++nt) {
            int col = (wave * 4 + nt) * 16 + lr;
            float bov = bo[col];
            #pragma unroll
            for (int reg = 0; reg < 4; ++reg) {
                int row = quad * 4 + reg;
                float v = x[(tq0 + row) * DM + col] + (aw[nt][reg] + bov) * rwv;
                oval[nt][reg] = v;
                xs2[row][col] = v;            // stage for LN / fragments
            }
        }
    }
    __syncthreads();    // xs2 complete (cross-wave reads follow)

    // ---- FFN phase (16 tokens) — math identical to standalone ffn ----
    {
        int tok = tid >> 4, l = tid & 15;
        float s = 0.f, s2 = 0.f;
        #pragma unroll
        for (int i = 0; i < 16; ++i) {
            float v = xs2[tok][l + 16 * i];
            s += v; s2 += v * v;
        }
        #pragma unroll
        for (int m = 1; m < 16; m <<= 1) { s += __shfl_xor(s, m); s2 += __shfl_xor(s2, m); }
        if (l == 0) {
            float mean = s * (1.f / 256.f);
            float var  = s2 * (1.f / 256.f) - mean * mean;
            stat_m[tok] = mean;
            stat_r[tok] = rsqrtf(var + 1e-5f);
        }
    }
    __syncthreads();

    // A-fragments (rows 0..15): wave handles kk = wave, wave+4
    for (int kk = wave; kk < 8; kk += 4) {
        int m = lr, k0 = kk * 32 + quad * 8;
        float mm = stat_m[m], rr = stat_r[m];
        unsigned int pk[4];
        #pragma unroll
        for (int jj = 0; jj < 4; ++jj) {
            int ka = k0 + 2 * jj, kb = ka + 1;
            float v0 = (xs2[m][ka] - mm) * rr * gf[ka] + bf[ka];
            float v1 = (xs2[m][kb] - mm) * rr * gf[kb] + bf[kb];
            pk[jj] = (unsigned int)f2bf(v0) | ((unsigned int)f2bf(v1) << 16);
        }
        *(uint4*)&Af[(kk * 64 + lane) * 8] = make_uint4(pk[0], pk[1], pk[2], pk[3]);
    }
    __syncthreads();

    short8 afr[8];
    #pragma unroll
    for (int kk = 0; kk < 8; ++kk)
        afr[kk] = *(const short8*)&Af[(kk * 64 + lane) * 8];
    __syncthreads();    // xs2/Af reads done before G overlays the pool

    // GEMM1: wave owns col-tiles ntg = wave*16+nt, nt=0..15
    for (int nt = 0; nt < 16; ++nt) {
        floatx4 acc = (floatx4){0.f, 0.f, 0.f, 0.f};
        const int ntg = wave * 16 + nt;
        #pragma unroll
        for (int kk = 0; kk < 8; ++kk) {
            short8 bfr = *(const short8*)(W1f + (size_t)((ntg * 8 + kk) * 64 + lane) * 8);
            acc = __builtin_amdgcn_mfma_f32_16x16x32_bf16(afr[kk], bfr, acc, 0, 0, 0);
        }
        const int n = ntg * 16 + lr;
        const float bb = b1f[n];
        #pragma unroll
        for (int reg = 0; reg < 4; ++reg) {
            int row = quad * 4 + reg;
            G[row][n] = f2bf(gelu_fast(acc[reg] + bb));
        }
    }
    __syncthreads();

    // GEMM2: wave owns col-tiles ct = wave*4+nt2, nt2=0..3
    floatx4 acc2[4];
    #pragma unroll
    for (int nt2 = 0; nt2 < 4; ++nt2) acc2[nt2] = (floatx4){0.f, 0.f, 0.f, 0.f};
    for (int kk2 = 0; kk2 < 32; ++kk2) {
        short8 a2 = *(const short8*)&G[lr][kk2 * 32 + quad * 8];
        #pragma unroll
        for (int nt2 = 0; nt2 < 4; ++nt2) {
            short8 b2 = *(const short8*)(W2f + (size_t)((((wave * 4 + nt2) * 32 + kk2) * 64 + lane) * 8));
            acc2[nt2] = __builtin_amdgcn_mfma_f32_16x16x32_bf16(a2, b2, acc2[nt2], 0, 0, 0);
        }
    }

    #pragma unroll
    for (int nt2 = 0; nt2 < 4; ++nt2) {
        int col = (wave * 4 + nt2) * 16 + lr;
        float bb = b2f[col];
        #pragma unroll
        for (int reg = 0; reg < 4; ++reg) {
            int row = quad * 4 + reg;
            float o = acc2[nt2][reg] + bb;
            out[(tq0 + row) * DM + col] = oval[nt2][reg] + o * rwv;
        }
    }
}

// ---------------------------------------------------------------------------
extern "C" void kernel_launch(void* const* d_in, const int* in_sizes, int n_in,
                              void* d_out, int out_size, void* d_ws, size_t ws_size,
                              hipStream_t stream)
{
    const float* x   = (const float*)d_in[0];
    const float* Wq  = (const float*)d_in[1];
    const float* bq  = (const float*)d_in[2];
    const float* Wk  = (const float*)d_in[3];
    const float* bk  = (const float*)d_in[4];
    const float* Wv  = (const float*)d_in[5];
    const float* bv  = (const float*)d_in[6];
    const float* Wo  = (const float*)d_in[7];
    const float* bo  = (const float*)d_in[8];
    const float* g1  = (const float*)d_in[9];
    const float* b1  = (const float*)d_in[10];
    const float* gf  = (const float*)d_in[11];
    const float* bf  = (const float*)d_in[12];
    const float* W1  = (const float*)d_in[13];
    const float* b1f = (const float*)d_in[14];
    const float* W2  = (const float*)d_in[15];
    const float* b2f = (const float*)d_in[16];
    const float* rw  = (const float*)d_in[17];
    float* out = (float*)d_out;

    // workspace (~43.3 MB): qn | kn | knTh/knTl | vall | knsq | W1f | W2f | Wvf | Wof
    float* ws   = (float*)d_ws;
    float* qn   = ws;                          // 2,097,152 floats
    float* kn   = ws + 2097152;                // 2,097,152
    unsigned short* knTh = (unsigned short*)(ws + 4194304);  // 2,097,152 shorts (4MB)
    unsigned short* knTl = knTh + 2097152;                   // 2,097,152 shorts (4MB)
    float* vall = ws + 6291456;                // 4,194,304
    float* knsq = ws + 10485760;               // 16,384
    unsigned short* W1f = (unsigned short*)(ws + 10502144);   // 262,144 shorts
    unsigned short* W2f = W1f + 262144;                       // 262,144
    unsigned short* Wvf = W2f + 262144;                       // 65,536
    unsigned short* Wof = Wvf + 65536;                        // 65,536

    conv_kernel<<<320, 256, 0, stream>>>(W1, W2, Wv, Wo, W1f, W2f, Wvf, Wof);
    proj_merged_kernel<<<2048 + BATCH * SEQ / 16, 256, 0, stream>>>(
        x, Wq, bq, Wk, bk, bv, g1, b1, Wvf,
        qn, kn, knTh, knTl, knsq, vall);
    attn_ffn_kernel<<<BATCH * SEQ / 16, 256, 0, stream>>>(
        x, qn, kn, knTh, knTl, knsq, vall, Wof, bo,
        gf, bf, W1f, b1f, W2f, b2f, rw, out);
}

// Round 17
// 326.003 us; speedup vs baseline: 1.0317x; 1.0014x over previous
//
#include <hip/hip_runtime.h>
#include <math.h>

#define BATCH 8
#define SEQ   2048
#define DM    256
#define DQK   128
#define NHEADS 8
#define NK    16
#define DFF   1024

typedef __attribute__((ext_vector_type(8))) short short8;
typedef __attribute__((ext_vector_type(8))) _Float16 half8;
typedef __attribute__((ext_vector_type(4))) float floatx4;
typedef unsigned long long ull;

__device__ __forceinline__ unsigned short f2bf(float f) {
    unsigned int u = __float_as_uint(f);
    u += 0x7fffu + ((u >> 16) & 1u);          // round-to-nearest-even
    return (unsigned short)(u >> 16);
}

__device__ __forceinline__ float gelu_fast(float h) {
    float y = 0.7978845608028654f * (h + 0.044715f * h * h * h);
    float e = __expf(2.f * y);
    float t = 1.f - 2.f / (e + 1.f);
    return 0.5f * h * (1.f + t);
}

// composite sort key: primary score desc, secondary idx asc. Unique per idx.
__device__ __forceinline__ ull mkkey(float f, int gidx) {
    unsigned int u = __float_as_uint(f);
    u ^= (unsigned int)((int)u >> 31) | 0x80000000u;   // sortable float
    return ((ull)u << 32) | (unsigned int)(2047 - gidx);
}

__device__ __forceinline__ ull shfl_xor_u64(ull v, int m) {
    unsigned int lo = (unsigned int)v, hi = (unsigned int)(v >> 32);
    lo = __shfl_xor(lo, m);
    hi = __shfl_xor(hi, m);
    return ((ull)hi << 32) | lo;
}

// ---------------------------------------------------------------------------
// Kernel W: repack W1/W2/Wv/Wo fp32 -> bf16 MFMA B-fragment order (verbatim).
// ---------------------------------------------------------------------------
__global__ __launch_bounds__(256) void conv_kernel(
    const float* __restrict__ W1, const float* __restrict__ W2,
    const float* __restrict__ Wv, const float* __restrict__ Wo,
    unsigned short* __restrict__ W1f, unsigned short* __restrict__ W2f,
    unsigned short* __restrict__ Wvf, unsigned short* __restrict__ Wof)
{
    int g = blockIdx.x * 256 + threadIdx.x;
    const float* W; unsigned short* O; int e, stride;
    if (g < 32768)      { W = W1; O = W1f; e = g;         stride = DFF; }
    else if (g < 65536) { W = W2; O = W2f; e = g - 32768; stride = DM;  }
    else if (g < 73728) { W = Wv; O = Wvf; e = g - 65536; stride = DM;  }
    else                { W = Wo; O = Wof; e = g - 73728; stride = DM;  }
    int lane = e & 63;
    int kk, nt;
    if (g < 32768)      { kk = (e >> 6) & 7;  nt = e >> 9;  }
    else if (g < 65536) { kk = (e >> 6) & 31; nt = e >> 11; }
    else                { kk = (e >> 6) & 7;  nt = e >> 9;  }
    int n = nt * 16 + (lane & 15);
    int k0 = kk * 32 + (lane >> 4) * 8;
    unsigned int pk[4];
    #pragma unroll
    for (int jj = 0; jj < 4; ++jj) {
        unsigned short lo = f2bf(W[(size_t)(k0 + 2 * jj) * stride + n]);
        unsigned short hi = f2bf(W[(size_t)(k0 + 2 * jj + 1) * stride + n]);
        pk[jj] = (unsigned int)lo | ((unsigned int)hi << 16);
    }
    *(uint4*)(O + (size_t)e * 8) = make_uint4(pk[0], pk[1], pk[2], pk[3]);
}

// ---------------------------------------------------------------------------
// Kernel P: MERGED projections (R14-measured: range split). Blocks 0..2047
// run the proj_qk path (R8 verbatim); blocks 2048..3071 run the proj_v
// path (verbatim). Shared memory = union pool -> 8 blocks/CU.
// ---------------------------------------------------------------------------
__global__ __launch_bounds__(256) void proj_merged_kernel(
    const float* __restrict__ x,
    const float* __restrict__ Wq, const float* __restrict__ bq,
    const float* __restrict__ Wk, const float* __restrict__ bk,
    const float* __restrict__ bv, const float* __restrict__ g1,
    const float* __restrict__ b1,
    const unsigned short* __restrict__ Wvf,
    float* __restrict__ qn, float* __restrict__ kn,
    unsigned short* __restrict__ knTh, unsigned short* __restrict__ knTl,
    float* __restrict__ knsq, float* __restrict__ vall)
{
    __shared__ __align__(16) char pool[19840];
    const int tid = threadIdx.x;

    if (blockIdx.x < 2048) {
        // ================= proj_qk path (R8 verbatim) =================
        float* ks = (float*)pool;                          // 8*128 floats
        float (*nred)[2]  = (float(*)[2])(pool + 4096);    // [8][2]
        float (*kred)[2]  = (float(*)[2])(pool + 4160);
        float (*k2red)[2] = (float(*)[2])(pool + 4224);

        const int b = blockIdx.x & 7;
        const int chunk = blockIdx.x >> 3;
        const size_t t0 = (size_t)b * SEQ + (size_t)chunk * 8;

        {
            const int col = tid & 127, half = tid >> 7;
            const int half_u = __builtin_amdgcn_readfirstlane(half);
            const float* xrow[4];
            #pragma unroll
            for (int t = 0; t < 4; ++t)
                xrow[t] = x + (t0 + (size_t)(half_u * 4 + t)) * DM;

            float qa[4] = {0.f, 0.f, 0.f, 0.f}, ka[4] = {0.f, 0.f, 0.f, 0.f};
            for (int d = 0; d < 256; d += 4) {
                float4 xv[4];
                #pragma unroll
                for (int t = 0; t < 4; ++t) xv[t] = *(const float4*)(xrow[t] + d);
                #pragma unroll
                for (int dd = 0; dd < 4; ++dd) {
                    float wq = Wq[(d + dd) * DQK + col];
                    float wk = Wk[(d + dd) * DQK + col];
                    #pragma unroll
                    for (int t = 0; t < 4; ++t) {
                        float xval = (dd == 0) ? xv[t].x : (dd == 1) ? xv[t].y
                                   : (dd == 2) ? xv[t].z : xv[t].w;
                        qa[t] = fmaf(xval, wq, qa[t]);
                        ka[t] = fmaf(xval, wk, ka[t]);
                    }
                }
            }
            #pragma unroll
            for (int t = 0; t < 4; ++t) { qa[t] += bq[col]; ka[t] += bk[col]; }

            const int sub = (tid >> 6) & 1;
            #pragma unroll
            for (int t = 0; t < 4; ++t) {
                float sq = qa[t] * qa[t], sk = ka[t] * ka[t];
                #pragma unroll
                for (int m = 1; m < 64; m <<= 1) { sq += __shfl_xor(sq, m); sk += __shfl_xor(sk, m); }
                if ((tid & 63) == 0) { nred[half * 4 + t][sub] = sq; kred[half * 4 + t][sub] = sk; }
            }
            __syncthreads();
            float kvv[4];
            #pragma unroll
            for (int t = 0; t < 4; ++t) {
                int tok = half * 4 + t;
                float nq = sqrtf(nred[tok][0] + nred[tok][1]);
                float nk = sqrtf(kred[tok][0] + kred[tok][1]);
                float qv = qa[t] / fmaxf(nq, 1e-12f);
                float kv = ka[t] / fmaxf(nk, 1e-12f);
                qn[(t0 + tok) * DQK + col] = qv;
                kn[(t0 + tok) * DQK + col] = kv;
                ks[tok * 128 + col] = kv;
                kvv[t] = kv;
            }
            #pragma unroll
            for (int t = 0; t < 4; ++t) {
                float s2 = kvv[t] * kvv[t];
                #pragma unroll
                for (int m = 1; m < 64; m <<= 1) s2 += __shfl_xor(s2, m);
                if ((tid & 63) == 0) k2red[half * 4 + t][sub] = s2;
            }
            __syncthreads();
            if (tid < 8) knsq[t0 + tid] = k2red[tid][0] + k2red[tid][1];
        }

        // --- K^T -> fp16 hi/lo B-fragments ---
        {
            const int e   = tid & 127;
            const int sel = tid >> 7;           // 0 = hi, 1 = lo(*4096)
            const int key = e & 7;
            const int kq  = e >> 3;             // kk*4 + qd
            const int kk  = kq >> 2, qd = kq & 3;
            const int nt  = chunk >> 1;
            const int n   = ((chunk & 1) << 3) + key;
            const float* src = &ks[key * 128 + kk * 32 + qd * 8];
            unsigned int pk[4];
            #pragma unroll
            for (int jj = 0; jj < 4; ++jj) {
                float v0 = src[2 * jj], v1 = src[2 * jj + 1];
                _Float16 h0 = (_Float16)v0, h1 = (_Float16)v1;
                unsigned short u0, u1;
                if (sel == 0) {
                    u0 = __builtin_bit_cast(unsigned short, h0);
                    u1 = __builtin_bit_cast(unsigned short, h1);
                } else {
                    _Float16 l0 = (_Float16)((v0 - (float)h0) * 4096.f);
                    _Float16 l1 = (_Float16)((v1 - (float)h1) * 4096.f);
                    u0 = __builtin_bit_cast(unsigned short, l0);
                    u1 = __builtin_bit_cast(unsigned short, l1);
                }
                pk[jj] = (unsigned int)u0 | ((unsigned int)u1 << 16);
            }
            unsigned short* dst = (sel ? knTl : knTh)
                + (size_t)b * 262144
                + (size_t)((nt * 4 + kk) * 64 + qd * 16 + n) * 8;
            *(uint4*)dst = make_uint4(pk[0], pk[1], pk[2], pk[3]);
        }
    } else {
        // ================= proj_v path (verbatim) =================
        float (*xs)[260] = (float(*)[260])pool;            // 16640B
        float* stat_m = (float*)(pool + 16640);            // 64B
        float* stat_r = (float*)(pool + 16704);            // 64B
        float* bvs = (float*)(pool + 16768);               // 1024B
        float* g1s = (float*)(pool + 17792);               // 1024B
        float* b1s = (float*)(pool + 18816);               // 1024B

        const int lane = tid & 63, wave = tid >> 6;
        const int quad = lane >> 4, lr = lane & 15;
        const size_t t0 = (size_t)(blockIdx.x - 2048) * 16;

        for (int i = tid; i < 16 * 256; i += 256) xs[i >> 8][i & 255] = x[t0 * DM + i];
        bvs[tid] = bv[tid]; g1s[tid] = g1[tid]; b1s[tid] = b1[tid];
        __syncthreads();

        {
            int tok = tid >> 4, l = tid & 15;
            float s = 0.f, s2 = 0.f;
            #pragma unroll
            for (int i = 0; i < 16; ++i) {
                float v = xs[tok][l + 16 * i];
                s += v; s2 += v * v;
            }
            #pragma unroll
            for (int m = 1; m < 16; m <<= 1) { s += __shfl_xor(s, m); s2 += __shfl_xor(s2, m); }
            if (l == 0) {
                float mean = s * (1.f / 256.f);
                float var  = s2 * (1.f / 256.f) - mean * mean;
                stat_m[tok] = mean;
                stat_r[tok] = rsqrtf(var + 1e-5f);
            }
        }
        __syncthreads();

        short8 av[8];
        {
            float mm = stat_m[lr], rr = stat_r[lr];
            #pragma unroll
            for (int kk = 0; kk < 8; ++kk) {
                #pragma unroll
                for (int j = 0; j < 8; ++j) {
                    int k = kk * 32 + quad * 8 + j;
                    float v = (xs[lr][k] - mm) * rr * g1s[k] + b1s[k];
                    av[kk][j] = (short)f2bf(v);
                }
            }
        }
        floatx4 acc[4];
        #pragma unroll
        for (int nt = 0; nt < 4; ++nt) acc[nt] = (floatx4){0.f, 0.f, 0.f, 0.f};
        #pragma unroll
        for (int nt = 0; nt < 4; ++nt) {
            #pragma unroll
            for (int kk = 0; kk < 8; ++kk) {
                short8 bfr = *(const short8*)(Wvf + ((size_t)(((wave * 4 + nt) * 8 + kk) * 64) + lane) * 8);
                acc[nt] = __builtin_amdgcn_mfma_f32_16x16x32_bf16(av[kk], bfr, acc[nt], 0, 0, 0);
            }
        }
        #pragma unroll
        for (int nt = 0; nt < 4; ++nt) {
            int col = (wave * 4 + nt) * 16 + lr;
            float bb = bvs[col];
            #pragma unroll
            for (int reg = 0; reg < 4; ++reg) {
                int row = quad * 4 + reg;
                vall[(t0 + row) * DM + col] = acc[nt][reg] + bb;
            }
        }
    }
}

// ---------------------------------------------------------------------------
// Kernel B: FUSED attn + ffn, 16 tokens/block. R14 structure; the ONLY change
// vs R16: the selection (stream top-2, per-quarter tournament, merge) runs
// the subgroup's TWO queries' chains INTERLEAVED (q0/q1 alternating per
// stage) — two independent dependency chains hide each other's shuffle
// latency. Per-query op sequence unchanged -> topidx bit-identical.
// ---------------------------------------------------------------------------
__global__ __launch_bounds__(256, 4) void attn_ffn_kernel(
    const float* __restrict__ x,
    const float* __restrict__ qn_g, const float* __restrict__ kn_g,
    const unsigned short* __restrict__ knTh, const unsigned short* __restrict__ knTl,
    const float* __restrict__ knsq_g,
    const float* __restrict__ vall,
    const unsigned short* __restrict__ Wof, const float* __restrict__ bo,
    const float* __restrict__ gf, const float* __restrict__ bf,
    const unsigned short* __restrict__ W1f, const float* __restrict__ b1f,
    const unsigned short* __restrict__ W2f, const float* __restrict__ b2f,
    const float* __restrict__ rw, float* __restrict__ out)
{
    __shared__ __align__(16) char pool[33024];
    __shared__ float stat_m[16], stat_r[16];
    float* s_ld   = (float*)pool;                       // 16x512 scores (32KB)
    float* attn_s = s_ld;                               // 16*128
    float* o8     = s_ld + 2048;                        // 16*260 (stride 260)
    float (*xs2)[260] = (float(*)[260])pool;            // 16640B (overlay)
    unsigned short* Af = (unsigned short*)(pool + 16640); // 8192B
    unsigned short (*G)[1032] = (unsigned short(*)[1032])pool; // 33024B (overlay)

    const int tid = threadIdx.x;
    const int lane = tid & 63, wave = tid >> 6;
    const int quad = lane >> 4, lr = lane & 15;
    const int sg = lane >> 5, sl = lane & 31;     // 32-lane subgroup
    const int sgid = wave * 2 + sg;               // 0..7
    const int b = blockIdx.x & 7;
    const int chunk = blockIdx.x >> 3;            // 0..127
    const size_t tq0 = (size_t)b * SEQ + (size_t)chunk * 16;
    const size_t rowb = (size_t)b * SEQ;

    half8 a_hi[4], a_lo[4];
    {
        const float* qrow = qn_g + (tq0 + lr) * DQK + quad * 8;
        #pragma unroll
        for (int kk = 0; kk < 4; ++kk) {
            float4 fa = *(const float4*)(qrow + kk * 32);
            float4 fb = *(const float4*)(qrow + kk * 32 + 4);
            float vv[8] = {fa.x, fa.y, fa.z, fa.w, fb.x, fb.y, fb.z, fb.w};
            #pragma unroll
            for (int j = 0; j < 8; ++j) {
                float v = vv[j];
                _Float16 h = (_Float16)v;
                a_hi[kk][j] = h;
                a_lo[kk][j] = (_Float16)((v - (float)h) * 4096.f);
            }
        }
    }

    const unsigned short* bh = knTh + (size_t)b * 262144;
    const unsigned short* bl = knTl + (size_t)b * 262144;
    const float* ksqb = knsq_g + rowb;

    ull c0[2], c1[2];          // candidate regs: lane sl holds ranks sl, sl+32

    for (int q4 = 0; q4 < 4; ++q4) {
        if (q4) __syncthreads();

        for (int t = 0; t < 8; ++t) {
            const int tile = q4 * 32 + wave * 8 + t;
            const unsigned short* ph = bh + (size_t)tile * 2048 + lane * 8;
            const unsigned short* pl = bl + (size_t)tile * 2048 + lane * 8;
            floatx4 am  = (floatx4){0.f, 0.f, 0.f, 0.f};
            floatx4 ax1 = (floatx4){0.f, 0.f, 0.f, 0.f};
            floatx4 ax2 = (floatx4){0.f, 0.f, 0.f, 0.f};
            #pragma unroll
            for (int kk = 0; kk < 4; ++kk) {
                half8 bhf = *(const half8*)(ph + kk * 512);
                half8 blf = *(const half8*)(pl + kk * 512);
                am  = __builtin_amdgcn_mfma_f32_16x16x32_f16(a_hi[kk], bhf, am,  0, 0, 0);
                ax1 = __builtin_amdgcn_mfma_f32_16x16x32_f16(a_hi[kk], blf, ax1, 0, 0, 0);
                ax2 = __builtin_amdgcn_mfma_f32_16x16x32_f16(a_lo[kk], bhf, ax2, 0, 0, 0);
            }
            const int keyloc = (wave * 8 + t) * 16 + lr;
            const float kq = ksqb[q4 * 512 + keyloc];
            #pragma unroll
            for (int r = 0; r < 4; ++r) {
                s_ld[(quad * 4 + r) * 512 + keyloc] =
                    2.f * (am[r] + (ax1[r] + ax2[r]) * (1.f / 4096.f)) - kq;
            }
        }
        __syncthreads();

        // ---- per-quarter top-16: BOTH queries' chains interleaved ----
        {
            const float* srow0 = &s_ld[(sgid    ) * 512 + sl];
            const float* srow1 = &s_ld[(sgid + 8) * 512 + sl];
            // stream: exact composite top-2 per lane, per query (interleaved)
            float f0a = -INFINITY, f1a = -INFINITY; int i0a = 0, i1a = 0;
            float f0b = -INFINITY, f1b = -INFINITY; int i0b = 0, i1b = 0;
            #pragma unroll
            for (int i = 0; i < 16; ++i) {
                const int gidx = q4 * 512 + sl + 32 * i;
                float fa = srow0[32 * i];
                float fb = srow1[32 * i];
                bool aa = fa > f0a, ba = fa > f1a;
                f1a = aa ? f0a : (ba ? fa   : f1a);
                i1a = aa ? i0a : (ba ? gidx : i1a);
                f0a = aa ? fa   : f0a;
                i0a = aa ? gidx : i0a;
                bool ab = fb > f0b, bb2 = fb > f1b;
                f1b = ab ? f0b : (bb2 ? fb   : f1b);
                i1b = ab ? i0b : (bb2 ? gidx : i1b);
                f0b = ab ? fb   : f0b;
                i0b = ab ? gidx : i0b;
            }
            ull k2va = mkkey(f1a, i1a), cura = mkkey(f0a, i0a);
            ull k2vb = mkkey(f1b, i1b), curb = mkkey(f0b, i0b);
            int cnta = 0, cntb = 0;
            for (int r = 0; r < NK; ++r) {
                ull wa = cura, wb = curb;
                #pragma unroll
                for (int m = 1; m < 32; m <<= 1) {     // two independent chains
                    ull oa = shfl_xor_u64(wa, m);
                    ull ob = shfl_xor_u64(wb, m);
                    if (oa > wa) wa = oa;
                    if (ob > wb) wb = ob;
                }
                const int slot = q4 * 16 + r;
                if (sl == slot)      { c0[0] = wa; c0[1] = wb; }
                if (sl == slot - 32) { c1[0] = wa; c1[1] = wb; }
                if (cura == wa) {                      // unique key -> one lane pops
                    ++cnta;
                    if (cnta == 1) cura = k2va;
                    else {
                        // rare: 3rd+ pop -> exact rescan below popped key
                        ull best = 0;
                        #pragma unroll
                        for (int i = 0; i < 16; ++i) {
                            ull k = mkkey(srow0[32 * i], q4 * 512 + sl + 32 * i);
                            if (k < wa && k > best) best = k;
                        }
                        cura = best;
                    }
                }
                if (curb == wb) {
                    ++cntb;
                    if (cntb == 1) curb = k2vb;
                    else {
                        ull best = 0;
                        #pragma unroll
                        for (int i = 0; i < 16; ++i) {
                            ull k = mkkey(srow1[32 * i], q4 * 512 + sl + 32 * i);
                            if (k < wb && k > best) best = k;
                        }
                        curb = best;
                    }
                }
            }
        }
    }
    __syncthreads();

    // ---- exact merge: both queries interleaved; lane sl takes rank sl ----
    int tidx[2] = {0, 0};
    {
        ull caa = c0[0], cba = c1[0];
        ull hia = caa > cba ? caa : cba, loa = caa > cba ? cba : caa;
        ull cab = c0[1], cbb = c1[1];
        ull hib = cab > cbb ? cab : cbb, lob = cab > cbb ? cbb : cab;
        ull cura = hia, curb = hib;
        int cnta = 0, cntb = 0;
        for (int r = 0; r < NK; ++r) {
            ull wa = cura, wb = curb;
            #pragma unroll
            for (int m = 1; m < 32; m <<= 1) {
                ull oa = shfl_xor_u64(wa, m);
                ull ob = shfl_xor_u64(wb, m);
                if (oa > wa) wa = oa;
                if (ob > wb) wb = ob;
            }
            if (sl == r) {
                tidx[0] = 2047 - (int)(unsigned int)(wa & 0xFFFFFFFFull);
                tidx[1] = 2047 - (int)(unsigned int)(wb & 0xFFFFFFFFull);
            }
            if (cura == wa) { ++cnta; cura = (cnta == 1) ? loa : 0ull; }
            if (curb == wb) { ++cntb; curb = (cntb == 1) ? lob : 0ull; }
        }
    }

    #pragma unroll
    for (int qq = 0; qq < 4; ++qq) {
        const int sgq = qq & 1;
        const int qiq = qq >> 1;
        const int q   = wave * 2 + sgq + 8 * qiq;
        const int srcb = sgq * 32;
        const int h = lane >> 3;
        const int k1 = lane & 7, k2 = 8 + (lane & 7);
        const int i1 = __shfl(tidx[qiq], srcb + k1);
        const int i2 = __shfl(tidx[qiq], srcb + k2);
        const float* qrow = qn_g + (tq0 + q) * DQK + h * 16;
        const float* kr1 = kn_g + (rowb + i1) * DQK + h * 16;
        const float* kr2 = kn_g + (rowb + i2) * DQK + h * 16;
        float lg1 = 0.f, lg2 = 0.f;
        #pragma unroll
        for (int d = 0; d < 16; d += 4) {
            float4 qv = *(const float4*)&qrow[d];
            float4 a1 = *(const float4*)&kr1[d];
            float4 a2 = *(const float4*)&kr2[d];
            lg1 = fmaf(qv.x, a1.x, lg1); lg1 = fmaf(qv.y, a1.y, lg1);
            lg1 = fmaf(qv.z, a1.z, lg1); lg1 = fmaf(qv.w, a1.w, lg1);
            lg2 = fmaf(qv.x, a2.x, lg2); lg2 = fmaf(qv.y, a2.y, lg2);
            lg2 = fmaf(qv.z, a2.z, lg2); lg2 = fmaf(qv.w, a2.w, lg2);
        }
        lg1 *= 0.25f; lg2 *= 0.25f;
        float mx = fmaxf(lg1, lg2);
        #pragma unroll
        for (int m = 1; m < 8; m <<= 1) mx = fmaxf(mx, __shfl_xor(mx, m));
        float e1 = expf(lg1 - mx), e2 = expf(lg2 - mx);
        float ssum = e1 + e2;
        #pragma unroll
        for (int m = 1; m < 8; m <<= 1) ssum += __shfl_xor(ssum, m);
        attn_s[q * 128 + h * 16 + k1] = e1 / ssum;
        attn_s[q * 128 + h * 16 + k2] = e2 / ssum;
        // within-wave LDS RAW: ordered by lgkmcnt, no barrier needed

        float o[4] = {0.f, 0.f, 0.f, 0.f};
        for (int k = 0; k < NK; ++k) {
            const int ik = __shfl(tidx[qiq], srcb + k);
            const float* vr = vall + (rowb + ik) * DM;
            #pragma unroll
            for (int j = 0; j < 4; ++j) {
                int d = lane + 64 * j;
                o[j] = fmaf(attn_s[q * 128 + (d >> 5) * 16 + k], vr[d], o[j]);
            }
        }
        #pragma unroll
        for (int j = 0; j < 4; ++j) o8[q * 260 + lane + 64 * j] = o[j];
    }
    __syncthreads();    // o8 is read cross-wave in the Wo phase

    // ---- Wo via bf16 MFMA; outputs stay in registers (oval) ----
    float rwv = rw[0];
    float oval[4][4];
    {
        short8 ao[8];
        #pragma unroll
        for (int kk = 0; kk < 8; ++kk) {
            #pragma unroll
            for (int j = 0; j < 8; ++j) {
                int k = kk * 32 + quad * 8 + j;
                ao[kk][j] = (short)f2bf(o8[lr * 260 + k]);
            }
        }
        __syncthreads();    // all o8 reads done; xs2 may overlay pool below
        floatx4 aw[4];
        #pragma unroll
        for (int nt = 0; nt < 4; ++nt) aw[nt] = (floatx4){0.f, 0.f, 0.f, 0.f};
        #pragma unroll
        for (int nt = 0; nt < 4; ++nt) {
            #pragma unroll
            for (int kk = 0; kk < 8; ++kk) {
                short8 bofr = *(const short8*)(Wof + ((size_t)(((wave * 4 + nt) * 8 + kk) * 64) + lane) * 8);
                aw[nt] = __builtin_amdgcn_mfma_f32_16x16x32_bf16(ao[kk], bofr, aw[nt], 0, 0, 0);
            }
        }
        #pragma unroll
        for (int nt = 0; nt < 4; ++nt) {
            int col = (wave * 4 + nt) * 16 + lr;
            float bov = bo[col];
            #pragma unroll
            for (int reg = 0; reg < 4; ++reg) {
                int row = quad * 4 + reg;
                float v = x[(tq0 + row) * DM + col] + (aw[nt][reg] + bov) * rwv;
                oval[nt][reg] = v;
                xs2[row][col] = v;            // stage for LN / fragments
            }
        }
    }
    __syncthreads();    // xs2 complete (cross-wave reads follow)

    // ---- FFN phase (16 tokens) — math identical to standalone ffn ----
    {
        int tok = tid >> 4, l = tid & 15;
        float s = 0.f, s2 = 0.f;
        #pragma unroll
        for (int i = 0; i < 16; ++i) {
            float v = xs2[tok][l + 16 * i];
            s += v; s2 += v * v;
        }
        #pragma unroll
        for (int m = 1; m < 16; m <<= 1) { s += __shfl_xor(s, m); s2 += __shfl_xor(s2, m); }
        if (l == 0) {
            float mean = s * (1.f / 256.f);
            float var  = s2 * (1.f / 256.f) - mean * mean;
            stat_m[tok] = mean;
            stat_r[tok] = rsqrtf(var + 1e-5f);
        }
    }
    __syncthreads();

    // A-fragments (rows 0..15): wave handles kk = wave, wave+4
    for (int kk = wave; kk < 8; kk += 4) {
        int m = lr, k0 = kk * 32 + quad * 8;
        float mm = stat_m[m], rr = stat_r[m];
        unsigned int pk[4];
        #pragma unroll
        for (int jj = 0; jj < 4; ++jj) {
            int ka = k0 + 2 * jj, kb = ka + 1;
            float v0 = (xs2[m][ka] - mm) * rr * gf[ka] + bf[ka];
            float v1 = (xs2[m][kb] - mm) * rr * gf[kb] + bf[kb];
            pk[jj] = (unsigned int)f2bf(v0) | ((unsigned int)f2bf(v1) << 16);
        }
        *(uint4*)&Af[(kk * 64 + lane) * 8] = make_uint4(pk[0], pk[1], pk[2], pk[3]);
    }
    __syncthreads();

    short8 afr[8];
    #pragma unroll
    for (int kk = 0; kk < 8; ++kk)
        afr[kk] = *(const short8*)&Af[(kk * 64 + lane) * 8];
    __syncthreads();    // xs2/Af reads done before G overlays the pool

    // GEMM1: wave owns col-tiles ntg = wave*16+nt, nt=0..15
    for (int nt = 0; nt < 16; ++nt) {
        floatx4 acc = (floatx4){0.f, 0.f, 0.f, 0.f};
        const int ntg = wave * 16 + nt;
        #pragma unroll
        for (int kk = 0; kk < 8; ++kk) {
            short8 bfr = *(const short8*)(W1f + (size_t)((ntg * 8 + kk) * 64 + lane) * 8);
            acc = __builtin_amdgcn_mfma_f32_16x16x32_bf16(afr[kk], bfr, acc, 0, 0, 0);
        }
        const int n = ntg * 16 + lr;
        const float bb = b1f[n];
        #pragma unroll
        for (int reg = 0; reg < 4; ++reg) {
            int row = quad * 4 + reg;
            G[row][n] = f2bf(gelu_fast(acc[reg] + bb));
        }
    }
    __syncthreads();

    // GEMM2: wave owns col-tiles ct = wave*4+nt2, nt2=0..3
    floatx4 acc2[4];
    #pragma unroll
    for (int nt2 = 0; nt2 < 4; ++nt2) acc2[nt2] = (floatx4){0.f, 0.f, 0.f, 0.f};
    for (int kk2 = 0; kk2 < 32; ++kk2) {
        short8 a2 = *(const short8*)&G[lr][kk2 * 32 + quad * 8];
        #pragma unroll
        for (int nt2 = 0; nt2 < 4; ++nt2) {
            short8 b2 = *(const short8*)(W2f + (size_t)((((wave * 4 + nt2) * 32 + kk2) * 64 + lane) * 8));
            acc2[nt2] = __builtin_amdgcn_mfma_f32_16x16x32_bf16(a2, b2, acc2[nt2], 0, 0, 0);
        }
    }

    #pragma unroll
    for (int nt2 = 0; nt2 < 4; ++nt2) {
        int col = (wave * 4 + nt2) * 16 + lr;
        float bb = b2f[col];
        #pragma unroll
        for (int reg = 0; reg < 4; ++reg) {
            int row = quad * 4 + reg;
            float o = acc2[nt2][reg] + bb;
            out[(tq0 + row) * DM + col] = oval[nt2][reg] + o * rwv;
        }
    }
}

// ---------------------------------------------------------------------------
extern "C" void kernel_launch(void* const* d_in, const int* in_sizes, int n_in,
                              void* d_out, int out_size, void* d_ws, size_t ws_size,
                              hipStream_t stream)
{
    const float* x   = (const float*)d_in[0];
    const float* Wq  = (const float*)d_in[1];
    const float* bq  = (const float*)d_in[2];
    const float* Wk  = (const float*)d_in[3];
    const float* bk  = (const float*)d_in[4];
    const float* Wv  = (const float*)d_in[5];
    const float* bv  = (const float*)d_in[6];
    const float* Wo  = (const float*)d_in[7];
    const float* bo  = (const float*)d_in[8];
    const float* g1  = (const float*)d_in[9];
    const float* b1  = (const float*)d_in[10];
    const float* gf  = (const float*)d_in[11];
    const float* bf  = (const float*)d_in[12];
    const float* W1  = (const float*)d_in[13];
    const float* b1f = (const float*)d_in[14];
    const float* W2  = (const float*)d_in[15];
    const float* b2f = (const float*)d_in[16];
    const float* rw  = (const float*)d_in[17];
    float* out = (float*)d_out;

    // workspace (~43.3 MB): qn | kn | knTh/knTl | vall | knsq | W1f | W2f | Wvf | Wof
    float* ws   = (float*)d_ws;
    float* qn   = ws;                          // 2,097,152 floats
    float* kn   = ws + 2097152;                // 2,097,152
    unsigned short* knTh = (unsigned short*)(ws + 4194304);  // 2,097,152 shorts (4MB)
    unsigned short* knTl = knTh + 2097152;                   // 2,097,152 shorts (4MB)
    float* vall = ws + 6291456;                // 4,194,304
    float* knsq = ws + 10485760;               // 16,384
    unsigned short* W1f = (unsigned short*)(ws + 10502144);   // 262,144 shorts
    unsigned short* W2f = W1f + 262144;                       // 262,144
    unsigned short* Wvf = W2f + 262144;                       // 65,536
    unsigned short* Wof = Wvf + 65536;                        // 65,536

    conv_kernel<<<320, 256, 0, stream>>>(W1, W2, Wv, Wo, W1f, W2f, Wvf, Wof);
    proj_merged_kernel<<<2048 + BATCH * SEQ / 16, 256, 0, stream>>>(
        x, Wq, bq, Wk, bk, bv, g1, b1, Wvf,
        qn, kn, knTh, knTl, knsq, vall);
    attn_ffn_kernel<<<BATCH * SEQ / 16, 256, 0, stream>>>(
        x, qn, kn, knTh, knTl, knsq, vall, Wof, bo,
        gf, bf, W1f, b1f, W2f, b2f, rw, out);
}